// Round 1
// baseline (205.612 us; speedup 1.0000x reference)
//
#include <hip/hip_runtime.h>

// x: [8, 1, 160, 160, 160] fp32; log_sigma: [3] fp32; out: scalar fp32.
// loss = -(sum over 3816 (axis,b,pair) of exp(-sq/(2*sigma_axis^2))) / 3816.
//
// R7: OCCUPANCY FIX. R1-R6 all showed OccupancyPercent ~13.5% ~= 1 wave/SIMD,
// the signature of VGPR_Count > 256 (full-unroll load hoisting). At 1
// wave/SIMD all HBM latency is exposed serially -> duration tracked
// instruction count, not bytes (~2.5 TB/s vs the 7 TB/s the harness fill
// hits). Fix: __launch_bounds__(320,4) caps VGPR at 128 (4 waves/SIMD), and
// the d-loop becomes an explicit depth-1 rolling prefetch (load slice it+1
// into n* while computing slice it in v*; d-diff folded into the handoff so
// the separate p0..p3 copy set is gone). Live state ~2 slices x 5 float4 +
// 13 accumulators ~= 85 VGPR, no spill expected. Work/bytes identical to R6
// (29 float4 loads/thread). ws contract and reduce/final unchanged.

constexpr int Wd4 = 40;              // float4 per row
constexpr int SLICE4 = 6400;         // float4 per slice
constexpr long BSTR4 = 160L * 6400;  // float4 per batch
constexpr int NB = 8;
constexpr int NPAIR = 159;
constexpr int NKEY = 3 * NB * NPAIR;   // 3816
constexpr int SLOT = 200;              // floats/slot: [0..4]=D [5..36]=H [37..196]=W
constexpr int NBLK = NB * 160;         // 8 b x 32 d-segs x 5 h-chunks = 1280
constexpr int PART_OFF = NBLK * SLOT;  // float offset of reduce partials in ws
constexpr int NFIN = 60;

__device__ __forceinline__ float sq4(const float4& a, const float4& c) {
    float e0 = a.x - c.x, e1 = a.y - c.y, e2 = a.z - c.z, e3 = a.w - c.w;
    return e0 * e0 + e1 * e1 + e2 * e2 + e3 * e3;
}

// 1280 blocks x 320 threads. bid -> (b, ds 0..31, hc 0..4). Thread: c4=t%40,
// rp=t/40 owns rows h0+4rp+{0..3}. Slices d0..d0+4 owned, d0+5 halo (v only).
__global__ __launch_bounds__(320, 4) void diff3_kernel(const float* __restrict__ x,
                                                       float* __restrict__ ws) {
    __shared__ float lds[1504];  // H: [0..1311] 32 keys*41; D: [1472..1496]; W reuses [0..1439]

    const int t = threadIdx.x;
    const int bid = blockIdx.x;
    const int b = bid / 160;
    const int r2 = bid % 160;
    const int ds = r2 / 5;     // d-segment, d0 = 5*ds
    const int hc = r2 % 5;     // h-chunk,  h0 = 32*hc
    const int d0 = ds * 5, h0 = hc * 32;
    const bool lastSeg = (ds == 31);

    const int c4 = t % 40;
    const int rp = t / 40;                  // 0..7
    const int lane = t & 63;
    const int wv = t >> 6;                  // wave 0..4
    const bool hOK = !(hc == 4 && rp == 7); // row h0+4rp+4 <= 159
    const bool sOK = (c4 < 39);
    const bool fixB = (lane == 63) && sOK;  // shfl partner in next wave -> load

    const float4* base = (const float4*)x + (size_t)b * BSTR4 + (size_t)d0 * SLICE4
                       + (size_t)(h0 + 4 * rp) * Wd4 + c4;

    float aW[4] = {0.f, 0.f, 0.f, 0.f};
    float aH[4] = {0.f, 0.f, 0.f, 0.f};
    float aD[5] = {0.f, 0.f, 0.f, 0.f, 0.f};

    // ---- preload slice 0 into the "current" register set.
    float4 v0 = base[0];
    float4 v1 = base[Wd4];
    float4 v2 = base[2 * Wd4];
    float4 v3 = base[3 * Wd4];
    float4 hv;
    if (hOK) hv = base[4 * Wd4];
    float bx0 = 0.f, bx1 = 0.f, bx2 = 0.f, bx3 = 0.f;
    if (fixB) {  // cross-wave w-boundary partner: scalar loads (4 thr/block)
        bx0 = ((const float*)(base))[4];
        bx1 = ((const float*)(base + Wd4))[4];
        bx2 = ((const float*)(base + 2 * Wd4))[4];
        bx3 = ((const float*)(base + 3 * Wd4))[4];
    }

#pragma unroll
    for (int it = 0; it < 5; ++it) {
        // ---- prefetch slice it+1 (it==4: d-halo slice, v-only) BEFORE compute.
        const bool haveN = (it < 4) || !lastSeg;
        float4 n0, n1, n2, n3, nh;
        float nbx0 = 0.f, nbx1 = 0.f, nbx2 = 0.f, nbx3 = 0.f;
        if (haveN) {
            const float4* np = base + (size_t)(it + 1) * SLICE4;
            n0 = np[0];
            n1 = np[Wd4];
            n2 = np[2 * Wd4];
            n3 = np[3 * Wd4];
            if (it < 4) {
                if (hOK) nh = np[4 * Wd4];
                if (fixB) {
                    nbx0 = ((const float*)(np))[4];
                    nbx1 = ((const float*)(np + Wd4))[4];
                    nbx2 = ((const float*)(np + 2 * Wd4))[4];
                    nbx3 = ((const float*)(np + 3 * Wd4))[4];
                }
            }
        }

        // ---- compute on current slice (v*, hv, bx*) while prefetch is in flight.
        // w-boundary partner .x from lane+1 (same row, next float4)
        float s0 = __shfl_down(v0.x, 1, 64); if (fixB) s0 = bx0;
        float s1 = __shfl_down(v1.x, 1, 64); if (fixB) s1 = bx1;
        float s2 = __shfl_down(v2.x, 1, 64); if (fixB) s2 = bx2;
        float s3 = __shfl_down(v3.x, 1, 64); if (fixB) s3 = bx3;

        float dw;
        dw = v0.y - v0.x; aW[0] += dw * dw;
        dw = v0.z - v0.y; aW[1] += dw * dw;
        dw = v0.w - v0.z; aW[2] += dw * dw;
        dw = v1.y - v1.x; aW[0] += dw * dw;
        dw = v1.z - v1.y; aW[1] += dw * dw;
        dw = v1.w - v1.z; aW[2] += dw * dw;
        dw = v2.y - v2.x; aW[0] += dw * dw;
        dw = v2.z - v2.y; aW[1] += dw * dw;
        dw = v2.w - v2.z; aW[2] += dw * dw;
        dw = v3.y - v3.x; aW[0] += dw * dw;
        dw = v3.z - v3.y; aW[1] += dw * dw;
        dw = v3.w - v3.z; aW[2] += dw * dw;
        if (sOK) {
            dw = s0 - v0.w; aW[3] += dw * dw;
            dw = s1 - v1.w; aW[3] += dw * dw;
            dw = s2 - v2.w; aW[3] += dw * dw;
            dw = s3 - v3.w; aW[3] += dw * dw;
        }
        // h: 3 register-local pairs + 1 via hv
        aH[0] += sq4(v1, v0);
        aH[1] += sq4(v2, v1);
        aH[2] += sq4(v3, v2);
        if (hOK) aH[3] += sq4(hv, v3);
        // d: pair (it, it+1) lands in aD[it] at the handoff (no p0..p3 copies)
        if (haveN) {
            aD[it] += sq4(n0, v0) + sq4(n1, v1) + sq4(n2, v2) + sq4(n3, v3);
        }
        // rotate: next becomes current (SSA under full unroll; dead after it==4)
        v0 = n0; v1 = n1; v2 = n2; v3 = n3; hv = nh;
        bx0 = nbx0; bx1 = nbx1; bx2 = nbx2; bx3 = nbx3;
    }

    // ---- flush. Phase 1: H per-key scratch + D wave-reduce.
#pragma unroll
    for (int j = 0; j < 4; ++j) lds[(4 * rp + j) * 41 + c4] = aH[j];
#pragma unroll
    for (int j = 0; j < 5; ++j) {
        float dd = aD[j];
        for (int off = 32; off > 0; off >>= 1) dd += __shfl_down(dd, off, 64);
        if (lane == 0) lds[1472 + j * 5 + wv] = dd;
    }
    __syncthreads();
    float hsum = 0.f, dsum = 0.f;
    if (t < 32) {
        const float* src = &lds[t * 41];
        for (int i = 0; i < 40; ++i) hsum += src[i];
    }
    if (t < 5) {
        for (int w2 = 0; w2 < 5; ++w2) dsum += lds[1472 + t * 5 + w2];
    }
    __syncthreads();  // H region reads done; reuse for W
    // Phase 2: W per-key scratch (key 4c4+j, 8 contributors rp).
#pragma unroll
    for (int j = 0; j < 4; ++j) lds[(4 * c4 + j) * 9 + rp] = aW[j];
    __syncthreads();
    float wsum = 0.f;
    if (t < 160) {
        const float* src = &lds[t * 9];
        for (int i = 0; i < 8; ++i) wsum += src[i];
    }
    // Private slot write (no atomics; every slot float written).
    float* slot = ws + (size_t)bid * SLOT;
    if (t < 5)   slot[t] = dsum;
    if (t < 32)  slot[5 + t] = hsum;
    if (t < 160) slot[37 + t] = wsum;
}

// 60 blocks x 64 threads: one thread per (axis,b,pair); sums contributing slots.
__global__ __launch_bounds__(64) void reduce_kernel(const float* __restrict__ ws,
                                                    const float* __restrict__ log_sigma,
                                                    float* __restrict__ part) {
    const int gk = blockIdx.x * 64 + threadIdx.x;
    float kv = 0.f;
    if (gk < NKEY) {
        const int a = gk / (NB * NPAIR);
        const int rem = gk % (NB * NPAIR);
        const int b = rem / NPAIR;
        const int k = rem % NPAIR;
        const float f = -0.5f * expf(-2.f * log_sigma[a]);  // -1/(2*sigma^2)
        const float* bb = ws + (size_t)b * 160 * SLOT;
        float val = 0.f;
        if (a == 0) {        // D: key k -> ds=k/5, j=k%5, sum over 5 hc
            const int ds = k / 5, j = k % 5;
            const float* p = bb + (size_t)(ds * 5) * SLOT + j;
            for (int hc = 0; hc < 5; ++hc) val += p[hc * SLOT];
        } else if (a == 1) { // H: key k -> hc=k/32, kk=k%32, sum over 32 ds
            const int hc = k / 32, kk = k % 32;
            const float* p = bb + (size_t)hc * SLOT + 5 + kk;
            for (int ds = 0; ds < 32; ++ds) val += p[(size_t)(ds * 5) * SLOT];
        } else {             // W: key k, sum over all 160 (ds,hc)
            const float* p = bb + 37 + k;
            for (int i = 0; i < 160; ++i) val += p[(size_t)i * SLOT];
        }
        kv = expf(val * f);
    }
    for (int off = 32; off > 0; off >>= 1) kv += __shfl_down(kv, off, 64);
    if (threadIdx.x == 0) part[blockIdx.x] = kv;
}

__global__ __launch_bounds__(64) void final_kernel(const float* __restrict__ part,
                                                   float* __restrict__ out) {
    float v = (threadIdx.x < NFIN) ? part[threadIdx.x] : 0.f;
    for (int off = 32; off > 0; off >>= 1) v += __shfl_down(v, off, 64);
    if (threadIdx.x == 0) out[0] = -v / (float)NKEY;
}

extern "C" void kernel_launch(void* const* d_in, const int* in_sizes, int n_in,
                              void* d_out, int out_size, void* d_ws, size_t ws_size,
                              hipStream_t stream) {
    const float* x = (const float*)d_in[0];
    const float* log_sigma = (const float*)d_in[1];
    float* out = (float*)d_out;
    float* ws = (float*)d_ws;

    diff3_kernel<<<NBLK, 320, 0, stream>>>(x, ws);
    reduce_kernel<<<NFIN, 64, 0, stream>>>(ws, log_sigma, ws + PART_OFF);
    final_kernel<<<1, 64, 0, stream>>>(ws + PART_OFF, out);
}